// Round 1
// baseline (358.865 us; speedup 1.0000x reference)
//
#include <hip/hip_runtime.h>
#include <math.h>

// MPS path log-likelihood, rank-1 (Perron) reduction.
//
// Reference computes EN = E^34 (E = Au(x)Au + Ad(x)Ad, 576x576) then scans
// S <- S@AA_s / tot per spin with p = tr(S@AA_s)/tot. Since E is strictly
// positive with Perron gap ~0.12, EN is rank-1 to far below fp32 precision:
// EN ~ r l^T. The scan then closes over a 24x24 matrix V (left factor):
//   x_u = <V, Gu>, x_d = <V, Gd>,  Gu = Au R Au^T, Gd = Ad R Ad^T
//   logp += log(x_s) - log(x_u + x_d)
//   V <- A_s^T V A_s / (x_u + x_d)
// where R (right) / L (left) are Perron eigen-matrices of the transfer map.
// All reference normalizations are scale-invariant and drop out exactly.

#define CHI     24
#define CHI2    576          // 24*24
#define NPATH   16
#define NSPIN   34
#define NT      256          // threads per block (4 waves)
#define PITERS  40           // power-iteration steps (gap^40 << fp32 eps)

__global__ __launch_bounds__(NT) void mps_ll_kernel(
    const float* __restrict__ A,        // [2,24,24] row-major
    const int*   __restrict__ samples,  // [16,34]
    float*       __restrict__ out)      // [1], pre-zeroed
{
    __shared__ float sAu[CHI2], sAd[CHI2];
    __shared__ float sR[CHI2],  sL[CHI2];
    __shared__ float sP1[CHI2], sP2[CHI2], sQ1[CHI2], sQ2[CHI2];
    __shared__ float sGu[CHI2], sGd[CHI2];
    __shared__ float sV[CHI2],  sT[CHI2];
    __shared__ float sRed[16];          // cross-wave partials: [0..3]=xu, [8..11]=xd

    const int tid  = threadIdx.x;
    const int path = blockIdx.x;

    // ---- load A, init eigen iterates ----
    for (int k = tid; k < CHI2; k += NT) {
        sAu[k] = A[k];
        sAd[k] = A[CHI2 + k];
        sR[k]  = 1.0f;
        sL[k]  = 1.0f;
    }
    __syncthreads();

    // ---- power iteration for Perron right (R) and left (L) fixed points ----
    // R <- Au R Au^T + Ad R Ad^T ; L <- Au^T L Au + Ad^T L Ad
    // normalized each iter by previous R[0]/L[0] (positive) -> no reductions.
    for (int it = 0; it < PITERS; ++it) {
        // stage 1: P1 = Au*R, P2 = Ad*R, Q1 = Au^T*L, Q2 = Ad^T*L
        for (int k = tid; k < CHI2; k += NT) {
            const int i = k / CHI, j = k % CHI;
            float p1 = 0.f, p2 = 0.f, q1 = 0.f, q2 = 0.f;
            for (int m = 0; m < CHI; ++m) {
                const float rmj = sR[m * CHI + j];
                const float lmj = sL[m * CHI + j];
                p1 += sAu[i * CHI + m] * rmj;   // (Au R)[i,j]
                p2 += sAd[i * CHI + m] * rmj;   // (Ad R)[i,j]
                q1 += sAu[m * CHI + i] * lmj;   // (Au^T L)[i,j]
                q2 += sAd[m * CHI + i] * lmj;   // (Ad^T L)[i,j]
            }
            sP1[k] = p1; sP2[k] = p2; sQ1[k] = q1; sQ2[k] = q2;
        }
        // read old normalizers while R/L are stable (before the barrier that
        // releases stage-2 writers)
        const float invr = 1.0f / sR[0];
        const float invl = 1.0f / sL[0];
        __syncthreads();
        // stage 2: R = (P1*Au^T + P2*Ad^T)*invr ; L = (Q1*Au + Q2*Ad)*invl
        for (int k = tid; k < CHI2; k += NT) {
            const int i = k / CHI, j = k % CHI;
            float r = 0.f, l = 0.f;
            for (int m = 0; m < CHI; ++m) {
                r += sP1[i * CHI + m] * sAu[j * CHI + m]
                   + sP2[i * CHI + m] * sAd[j * CHI + m];
                l += sQ1[i * CHI + m] * sAu[m * CHI + j]
                   + sQ2[i * CHI + m] * sAd[m * CHI + j];
            }
            sR[k] = r * invr;
            sL[k] = l * invl;
        }
        __syncthreads();
    }

    // ---- Gu = Au R Au^T, Gd = Ad R Ad^T ; V0 = L ----
    for (int k = tid; k < CHI2; k += NT) {
        const int i = k / CHI, j = k % CHI;
        float p1 = 0.f, p2 = 0.f;
        for (int m = 0; m < CHI; ++m) {
            const float rmj = sR[m * CHI + j];
            p1 += sAu[i * CHI + m] * rmj;
            p2 += sAd[i * CHI + m] * rmj;
        }
        sP1[k] = p1; sP2[k] = p2;
        sV[k]  = sL[k];
    }
    __syncthreads();
    for (int k = tid; k < CHI2; k += NT) {
        const int i = k / CHI, j = k % CHI;
        float gu = 0.f, gd = 0.f;
        for (int m = 0; m < CHI; ++m) {
            gu += sP1[i * CHI + m] * sAu[j * CHI + m];
            gd += sP2[i * CHI + m] * sAd[j * CHI + m];
        }
        sGu[k] = gu; sGd[k] = gd;
    }
    __syncthreads();

    // ---- per-path scan ----
    const int wave = tid >> 6, lane = tid & 63;
    float logp = 0.0f;

    for (int t = 0; t < NSPIN; ++t) {
        // dots: xu = <V,Gu>, xd = <V,Gd>
        float pu = 0.f, pd = 0.f;
        for (int k = tid; k < CHI2; k += NT) {
            const float v = sV[k];
            pu += v * sGu[k];
            pd += v * sGd[k];
        }
        for (int off = 32; off > 0; off >>= 1) {
            pu += __shfl_down(pu, off);
            pd += __shfl_down(pd, off);
        }
        if (lane == 0) { sRed[wave] = pu; sRed[8 + wave] = pd; }
        __syncthreads();
        const float xu = sRed[0] + sRed[1] + sRed[2] + sRed[3];
        const float xd = sRed[8] + sRed[9] + sRed[10] + sRed[11];
        const float tot = xu + xd;
        const int   s   = samples[path * NSPIN + t];
        const float xs  = s ? xu : xd;
        logp += logf(xs) - logf(tot);   // all threads compute identically

        if (t < NSPIN - 1) {
            const float* sAs = s ? sAu : sAd;
            const float invtot = 1.0f / tot;
            // T = V * As
            for (int k = tid; k < CHI2; k += NT) {
                const int i = k / CHI, j = k % CHI;
                float acc = 0.f;
                for (int m = 0; m < CHI; ++m)
                    acc += sV[i * CHI + m] * sAs[m * CHI + j];
                sT[k] = acc;
            }
            __syncthreads();
            // V = As^T * T * invtot
            for (int k = tid; k < CHI2; k += NT) {
                const int i = k / CHI, j = k % CHI;
                float acc = 0.f;
                for (int m = 0; m < CHI; ++m)
                    acc += sAs[m * CHI + i] * sT[m * CHI + j];
                sV[k] = acc * invtot;
            }
            __syncthreads();
        }
    }

    if (tid == 0) atomicAdd(out, -logp);
}

extern "C" void kernel_launch(void* const* d_in, const int* in_sizes, int n_in,
                              void* d_out, int out_size, void* d_ws, size_t ws_size,
                              hipStream_t stream) {
    const float* A       = (const float*)d_in[0];   // [2,24,24]
    const int*   samples = (const int*)d_in[1];     // [16,34]
    float*       out     = (float*)d_out;           // [1]

    // d_out is re-poisoned before every timed launch; zero it for atomicAdd.
    hipMemsetAsync(out, 0, sizeof(float), stream);
    mps_ll_kernel<<<NPATH, NT, 0, stream>>>(A, samples, out);
}

// Round 2
// 132.312 us; speedup vs baseline: 2.7123x; 2.7123x over previous
//
#include <hip/hip_runtime.h>
#include <math.h>

// MPS path log-likelihood via rank-1 (Perron) reduction — round 2.
//
// EN = E^34 (E = Au(x)Au + Ad(x)Ad) is numerically rank-1: EN ~ u v^T with
// U = R (right Perron matrix: R <- Au R Au^T + Ad R Ad^T) and V0 = L (left:
// L <- Au^T L Au + Ad^T L Ad). Scan per spin s:
//   xu = <V,Gu>, xd = <V,Gd> (Gu = Au R Au^T, Gd = Ad R Ad^T)
//   ll += log(x_s) - log(xu+xd);  V <- As^T V As * 2^-7 (exact-scale, the
// per-step constant cancels inside log(x_s)-log(tot)).
//
// KEY: R, L, V, Gu, Gd are symmetric (maps preserve symmetry, inits are
// symmetric), so every matmul is dot(row,row) with ds_read_b128.
// Round-1 was LDS-port bound (~1 ds_read_b32 per FMA, ~320 us predicted from
// instr counts, 307 measured). This version: 3x3 register tiles per lane
// (8x8 lanes = 1 dense wave per matmul), static A rows held in VGPRs
// (occupancy irrelevant: 16 blocks on 256 CUs), transposed output-tile
// assignment in stage2 so the same register rows serve both stages.

#define CHI     24
#define CHI2    576
#define NPATH   16
#define NSPIN   34
#define NT      128          // 2 waves: wave0 = R-chain + dots, wave1 = L-chain + V-update
#define PITERS  12           // Perron gap ~0.1 -> 1e-12; budget is ~7e-3
#define SCALE_P   0.00390625f   // 1/256 per power iter (lambda ~ 288, exact pow2)
#define SCALE_SCAN 0.0078125f   // 1/128 per scan step (growth ~ 144, exact pow2)

__device__ __forceinline__ float hsum4(float4 a) {
    return (a.x + a.z) + (a.y + a.w);
}

__device__ __forceinline__ void fma4(float4& acc, const float4 a, const float4 b) {
    acc.x = fmaf(a.x, b.x, acc.x);
    acc.y = fmaf(a.y, b.y, acc.y);
    acc.z = fmaf(a.z, b.z, acc.z);
    acc.w = fmaf(a.w, b.w, acc.w);
}

__global__ __launch_bounds__(NT, 1) void mps_ll_kernel(
    const float* __restrict__ A,        // [2,24,24]
    const int*   __restrict__ samples,  // [16,34]
    float*       __restrict__ out)      // [1], pre-zeroed
{
    __shared__ alignas(16) float sAu[CHI2], sAd[CHI2], sAuT[CHI2], sAdT[CHI2];
    __shared__ alignas(16) float sR[CHI2], sV[CHI2];
    __shared__ alignas(16) float sP1[CHI2], sP2[CHI2], sQ1[CHI2], sQ2[CHI2];
    __shared__ alignas(16) float sGu[CHI2], sGd[CHI2];

    const int tid  = threadIdx.x;
    const int w    = tid >> 6;
    const int lane = tid & 63;
    const int path = blockIdx.x;

    // ---- phase 0: load A, build transposes, init R = L = ones ----
    for (int k = tid; k < CHI2; k += NT) {
        const int r = k / CHI, c = k % CHI;
        const float u = A[k], d = A[CHI2 + k];
        sAu[k] = u; sAd[k] = d;
        sAuT[c * CHI + r] = u; sAdT[c * CHI + r] = d;
        sR[k] = 1.0f; sV[k] = 1.0f;
    }
    __syncthreads();

    // ---- lane tile: (i0..i0+2, j0..j0+2), 8x8 tiles cover 24x24 ----
    const int ti = lane >> 3, tj = lane & 7;
    const int i0 = 3 * ti, j0 = 3 * tj;

    // ---- preload static operand rows i0..i0+2 into registers ----
    // wave0: Au/Ad rows (R-chain: R' = Au R Au^T + Ad R Ad^T, then G build)
    // wave1: AuT/AdT rows (L-chain: L' = Au^T L Au + Ad^T L Ad)
    float4 xa[3][6], xb[3][6];
    {
        const float* bA = (w == 0) ? sAu : sAuT;
        const float* bB = (w == 0) ? sAd : sAdT;
        #pragma unroll
        for (int a = 0; a < 3; ++a) {
            const float4* ra = (const float4*)(bA + (i0 + a) * CHI);
            const float4* rb = (const float4*)(bB + (i0 + a) * CHI);
            #pragma unroll
            for (int v = 0; v < 6; ++v) { xa[a][v] = ra[v]; xb[a][v] = rb[v]; }
        }
    }

    const float* S  = (w == 0) ? sR  : sV;   // symmetric iterate (rows == cols)
    float*       O1 = (w == 0) ? sP1 : sQ1;  // stage-1 products
    float*       O2 = (w == 0) ? sP2 : sQ2;
    float*       D  = (w == 0) ? sR  : sV;   // stage-2 destination

    // ---- power iterations; iteration PITERS doubles as the G-build for wave0 ----
    for (int it = 0; it <= PITERS; ++it) {
        // stage 1: O1[i0+a][j] = dot(xa_row_a, S_row_j), O2 likewise (S symmetric)
        #pragma unroll
        for (int jr = 0; jr < 3; ++jr) {
            const float4* vr = (const float4*)(S + (j0 + jr) * CHI);
            float4 r4[6];
            #pragma unroll
            for (int v = 0; v < 6; ++v) r4[v] = vr[v];
            #pragma unroll
            for (int a = 0; a < 3; ++a) {
                float4 a1 = {0.f,0.f,0.f,0.f}, a2 = {0.f,0.f,0.f,0.f};
                #pragma unroll
                for (int v = 0; v < 6; ++v) { fma4(a1, xa[a][v], r4[v]); fma4(a2, xb[a][v], r4[v]); }
                O1[(i0 + a) * CHI + j0 + jr] = hsum4(a1);
                O2[(i0 + a) * CHI + j0 + jr] = hsum4(a2);
            }
        }
        __syncthreads();
        // stage 2 (transposed tile assignment: this lane writes (j0+b, i0+a)):
        //   D[j0+b][i0+a] = (dot(O1_row_{j0+b}, xa_row_a) + dot(O2_row_{j0+b}, xb_row_a)) * s
        // Last iteration, wave0: split into Gu/Gd instead of summing into R.
        const bool gstep = (it == PITERS);
        #pragma unroll
        for (int b = 0; b < 3; ++b) {
            const float4* pr = (const float4*)(O1 + (j0 + b) * CHI);
            const float4* qr = (const float4*)(O2 + (j0 + b) * CHI);
            float4 p4[6], q4[6];
            #pragma unroll
            for (int v = 0; v < 6; ++v) { p4[v] = pr[v]; q4[v] = qr[v]; }
            #pragma unroll
            for (int a = 0; a < 3; ++a) {
                float4 a1 = {0.f,0.f,0.f,0.f}, a2 = {0.f,0.f,0.f,0.f};
                #pragma unroll
                for (int v = 0; v < 6; ++v) { fma4(a1, p4[v], xa[a][v]); fma4(a2, q4[v], xb[a][v]); }
                const float h1 = hsum4(a1), h2 = hsum4(a2);
                if (gstep && w == 0) {
                    sGu[(j0 + b) * CHI + i0 + a] = h1 * SCALE_P;
                    sGd[(j0 + b) * CHI + i0 + a] = h2 * SCALE_P;
                } else {
                    D[(j0 + b) * CHI + i0 + a] = (h1 + h2) * SCALE_P;
                }
            }
        }
        __syncthreads();
    }

    // ---- scan: wave0 computes trace dots + loglik, wave1 updates V ----
    {
        const int sp = (lane < NSPIN) ? samples[path * NSPIN + lane] : 0;
        const unsigned long long smask = __ballot(sp != 0);
        float ll = 0.0f;
        const float4* sV4  = (const float4*)sV;
        const float4* sGu4 = (const float4*)sGu;
        const float4* sGd4 = (const float4*)sGd;
        float4 m4[3][6];   // AsT rows i0..i0+2, loaded by wave1 each step

        for (int t = 0; t < NSPIN; ++t) {
            const int bit = (int)((smask >> t) & 1ull);
            if (w == 0) {
                // xu = <V,Gu>, xd = <V,Gd> over 144 float4 chunks
                float pu = 0.f, pd = 0.f;
                #pragma unroll
                for (int c = 0; c < 3; ++c) {
                    const int idx = lane + 64 * c;
                    if (idx < 144) {
                        const float4 v = sV4[idx], g = sGu4[idx], h = sGd4[idx];
                        pu = fmaf(v.x, g.x, pu); pu = fmaf(v.y, g.y, pu);
                        pu = fmaf(v.z, g.z, pu); pu = fmaf(v.w, g.w, pu);
                        pd = fmaf(v.x, h.x, pd); pd = fmaf(v.y, h.y, pd);
                        pd = fmaf(v.z, h.z, pd); pd = fmaf(v.w, h.w, pd);
                    }
                }
                #pragma unroll
                for (int off = 32; off > 0; off >>= 1) {
                    pu += __shfl_xor(pu, off);
                    pd += __shfl_xor(pd, off);
                }
                ll += __logf(bit ? pu : pd) - __logf(pu + pd);
            } else if (t < NSPIN - 1) {
                // stage 1: P[i0+a][j0+jr] = dot(AsT_row_{i0+a}, V_row_{j0+jr})
                const float* asT = bit ? sAuT : sAdT;
                #pragma unroll
                for (int a = 0; a < 3; ++a) {
                    const float4* mr = (const float4*)(asT + (i0 + a) * CHI);
                    #pragma unroll
                    for (int v = 0; v < 6; ++v) m4[a][v] = mr[v];
                }
                #pragma unroll
                for (int jr = 0; jr < 3; ++jr) {
                    const float4* vr = (const float4*)(sV + (j0 + jr) * CHI);
                    float4 r4[6];
                    #pragma unroll
                    for (int v = 0; v < 6; ++v) r4[v] = vr[v];
                    #pragma unroll
                    for (int a = 0; a < 3; ++a) {
                        float4 a1 = {0.f,0.f,0.f,0.f};
                        #pragma unroll
                        for (int v = 0; v < 6; ++v) fma4(a1, m4[a][v], r4[v]);
                        sP1[(i0 + a) * CHI + j0 + jr] = hsum4(a1);
                    }
                }
            }
            __syncthreads();
            if (w == 1 && t < NSPIN - 1) {
                // stage 2: V[j0+b][i0+a] = dot(P_row_{j0+b}, AsT_row_{i0+a}) / 128
                #pragma unroll
                for (int b = 0; b < 3; ++b) {
                    const float4* pr = (const float4*)(sP1 + (j0 + b) * CHI);
                    float4 p4[6];
                    #pragma unroll
                    for (int v = 0; v < 6; ++v) p4[v] = pr[v];
                    #pragma unroll
                    for (int a = 0; a < 3; ++a) {
                        float4 a1 = {0.f,0.f,0.f,0.f};
                        #pragma unroll
                        for (int v = 0; v < 6; ++v) fma4(a1, p4[v], m4[a][v]);
                        sV[(j0 + b) * CHI + i0 + a] = hsum4(a1) * SCALE_SCAN;
                    }
                }
            }
            __syncthreads();
        }

        if (w == 0 && lane == 0) atomicAdd(out, -ll);
    }
}

extern "C" void kernel_launch(void* const* d_in, const int* in_sizes, int n_in,
                              void* d_out, int out_size, void* d_ws, size_t ws_size,
                              hipStream_t stream) {
    const float* A       = (const float*)d_in[0];
    const int*   samples = (const int*)d_in[1];
    float*       out     = (float*)d_out;

    hipMemsetAsync(out, 0, sizeof(float), stream);
    mps_ll_kernel<<<NPATH, NT, 0, stream>>>(A, samples, out);
}